// Round 2
// baseline (286.460 us; speedup 1.0000x reference)
//
#include <hip/hip_runtime.h>
#include <math.h>

#define NROWS   65536
#define DIMS    64
#define KCODES  1024
#define RPB     16      // rows per block
#define NTHR    256

static constexpr size_t QST_OFF  = 0;         // quantized_st [65536*64]
static constexpr size_t LOSS_OFF = 4194304;   // loss scalar
static constexpr size_t PERP_OFF = 4194305;   // perplexity scalar
static constexpr size_t ENC_OFF  = 4194306;   // encodings [65536*1024]
static constexpr size_t IDX_OFF  = 71303170;  // encoding_indices [65536]
static constexpr size_t DIST_OFF = 71368706;  // distances [65536*1024]

// ||e_k||^2 replicating np.sum(np.square(emb), 0): axis-0 strided reduction is
// sequential row-by-row; square rounded separately from the add (no fma).
__global__ void enorm_kernel(const float* __restrict__ emb, float* __restrict__ enorm) {
    #pragma clang fp contract(off)
    int k = blockIdx.x * blockDim.x + threadIdx.x;   // 0..1023
    float s = 0.f;
    for (int d = 0; d < DIMS; ++d) {
        float e  = emb[(size_t)d * KCODES + k];
        float sq = e * e;
        s = s + sq;
    }
    enorm[k] = s;
}

__global__ __launch_bounds__(NTHR) void vq_main(
    const float* __restrict__ x, const float* __restrict__ emb,
    const float* __restrict__ enorm, float* __restrict__ out,
    float* __restrict__ counts, float* __restrict__ sqsum)
{
    #pragma clang fp contract(off)
    __shared__ float xs[RPB * DIMS];
    __shared__ float xn[RPB];
    __shared__ float wbv[RPB * 4]; __shared__ int wbi[RPB * 4];
    __shared__ int   winner[RPB];

    const int tid  = threadIdx.x;
    const int lane = tid & 63;
    const int wv   = tid >> 6;
    const size_t n0 = (size_t)blockIdx.x * RPB;

    // stage 16 input rows (1024 floats) into LDS, coalesced float4
    ((float4*)xs)[tid] = ((const float4*)(x + n0 * DIMS))[tid];
    __syncthreads();

    // ||x||^2 replicating numpy scalar pairwise_sum (n=64 path): 8 interleaved
    // accumulators, sequential adds, 3-level combine; square rounded separately.
    if (tid < RPB) {
        const float* xr = xs + tid * DIMS;
        float rr[8];
        #pragma unroll
        for (int j = 0; j < 8; ++j) { float v = xr[j]; rr[j] = v * v; }
        #pragma unroll
        for (int i = 8; i < 64; i += 8) {
            #pragma unroll
            for (int j = 0; j < 8; ++j) { float v = xr[i + j]; float sq = v * v; rr[j] = rr[j] + sq; }
        }
        xn[tid] = ((rr[0] + rr[1]) + (rr[2] + rr[3])) + ((rr[4] + rr[5]) + (rr[6] + rr[7]));
    }
    __syncthreads();

    const float e0 = enorm[tid], e1 = enorm[tid + 256],
                e2 = enorm[tid + 512], e3 = enorm[tid + 768];

    // dot products acc[r][j] = x_r . e_{tid+256j}: sequential over d with a
    // single fma accumulator — matches BLAS sgemm microkernel K-loop order.
    float acc[RPB][4];
    #pragma unroll
    for (int r = 0; r < RPB; ++r) { acc[r][0] = acc[r][1] = acc[r][2] = acc[r][3] = 0.f; }

    const float* ep = emb + tid;
    #pragma unroll 2
    for (int d = 0; d < DIMS; ++d) {
        float g0 = ep[0], g1 = ep[256], g2 = ep[512], g3 = ep[768];
        ep += KCODES;
        #pragma unroll
        for (int r = 0; r < RPB; ++r) {
            float xv = xs[r * DIMS + d];   // broadcast read, conflict-free
            acc[r][0] = fmaf(xv, g0, acc[r][0]);
            acc[r][1] = fmaf(xv, g1, acc[r][1]);
            acc[r][2] = fmaf(xv, g2, acc[r][2]);
            acc[r][3] = fmaf(xv, g3, acc[r][3]);
        }
    }

    float* distb = out + DIST_OFF;
    float* encb  = out + ENC_OFF;

    #pragma unroll
    for (int r = 0; r < RPB; ++r) {
        const float xnr = xn[r];
        // replicate np expression order: (xn - 2*M) + en, each op rounded
        float m0 = 2.0f * acc[r][0]; float t0 = xnr - m0; float d0 = t0 + e0;
        float m1 = 2.0f * acc[r][1]; float t1 = xnr - m1; float d1 = t1 + e1;
        float m2 = 2.0f * acc[r][2]; float t2 = xnr - m2; float d2 = t2 + e2;
        float m3 = 2.0f * acc[r][3]; float t3 = xnr - m3; float d3 = t3 + e3;

        float* dr = distb + (n0 + r) * (size_t)KCODES;
        dr[tid] = d0; dr[tid + 256] = d1; dr[tid + 512] = d2; dr[tid + 768] = d3;
        float* er = encb + (n0 + r) * (size_t)KCODES;
        er[tid] = 0.f; er[tid + 256] = 0.f; er[tid + 512] = 0.f; er[tid + 768] = 0.f;

        // local argmin over the 4 codes, ascending index (strict less = first-idx tie-break)
        float bv = d0; int bi = tid;
        if (d1 < bv) { bv = d1; bi = tid + 256; }
        if (d2 < bv) { bv = d2; bi = tid + 512; }
        if (d3 < bv) { bv = d3; bi = tid + 768; }

        // wave-wide argmin butterfly with index tie-break (smaller index wins on equal)
        #pragma unroll
        for (int m = 1; m < 64; m <<= 1) {
            float ov = __shfl_xor(bv, m); int oi = __shfl_xor(bi, m);
            if (ov < bv || (ov == bv && oi < bi)) { bv = ov; bi = oi; }
        }
        if (lane == 0) { wbv[r * 4 + wv] = bv; wbi[r * 4 + wv] = bi; }
    }

    __syncthreads();   // also orders encodings zero-stores before the 1.0 store

    if (tid < RPB) {
        float bv = wbv[tid * 4]; int bi = wbi[tid * 4];
        for (int w = 1; w < 4; ++w) {
            float ov = wbv[tid * 4 + w]; int oi = wbi[tid * 4 + w];
            if (ov < bv || (ov == bv && oi < bi)) { bv = ov; bi = oi; }
        }
        winner[tid] = bi;
        out[IDX_OFF + n0 + tid] = (float)bi;
        atomicAdd(&counts[bi], 1.0f);
        encb[(n0 + tid) * (size_t)KCODES + bi] = 1.0f;
    }
    __syncthreads();

    // gather winner embedding, write quantized_st, accumulate squared error
    {
        int r  = tid >> 4;
        int dd = (tid & 15) * 4;
        int kk = winner[r];
        float4 q;
        q.x = emb[(size_t)(dd + 0) * KCODES + kk];
        q.y = emb[(size_t)(dd + 1) * KCODES + kk];
        q.z = emb[(size_t)(dd + 2) * KCODES + kk];
        q.w = emb[(size_t)(dd + 3) * KCODES + kk];
        *(float4*)(out + QST_OFF + (n0 + r) * DIMS + dd) = q;
        float f0 = q.x - xs[r*DIMS+dd+0], f1 = q.y - xs[r*DIMS+dd+1];
        float f2 = q.z - xs[r*DIMS+dd+2], f3 = q.w - xs[r*DIMS+dd+3];
        float ls = f0*f0 + f1*f1 + f2*f2 + f3*f3;
        #pragma unroll
        for (int m = 1; m < 64; m <<= 1) ls += __shfl_xor(ls, m);
        if (lane == 0) atomicAdd(sqsum, ls);
    }
}

__global__ void vq_final(const float* __restrict__ counts, const float* __restrict__ sqsum,
                         float* __restrict__ out) {
    __shared__ float part[16];
    int tid = threadIdx.x;  // 1024 threads
    float p = counts[tid] * (1.0f / 65536.0f);
    float t = p * logf(p + 1e-10f);
    #pragma unroll
    for (int m = 1; m < 64; m <<= 1) t += __shfl_xor(t, m);
    if ((tid & 63) == 0) part[tid >> 6] = t;
    __syncthreads();
    if (tid == 0) {
        float s = 0.f;
        #pragma unroll
        for (int i = 0; i < 16; ++i) s += part[i];
        out[LOSS_OFF] = 1.25f * sqsum[0] * (1.0f / 4194304.0f);  // q_loss + 0.25*e_loss
        out[PERP_OFF] = expf(-s);
    }
}

extern "C" void kernel_launch(void* const* d_in, const int* in_sizes, int n_in,
                              void* d_out, int out_size, void* d_ws, size_t ws_size,
                              hipStream_t stream) {
    const float* x   = (const float*)d_in[0];   // (64,32,32,64) fp32
    const float* emb = (const float*)d_in[1];   // (64,1024) fp32
    float* out    = (float*)d_out;
    float* enorm  = (float*)d_ws;      // [1024]
    float* counts = enorm + KCODES;    // [1024]
    float* sqsum  = counts + KCODES;   // [1]

    // ws is poisoned once and never re-poisoned: zero accumulators every call
    hipMemsetAsync(counts, 0, (KCODES + 1) * sizeof(float), stream);
    enorm_kernel<<<KCODES / NTHR, NTHR, 0, stream>>>(emb, enorm);
    vq_main<<<NROWS / RPB, NTHR, 0, stream>>>(x, emb, enorm, out, counts, sqsum);
    vq_final<<<1, KCODES, 0, stream>>>(counts, sqsum, out);
}

// Round 3
// 270.626 us; speedup vs baseline: 1.0585x; 1.0585x over previous
//
#include <hip/hip_runtime.h>
#include <math.h>

#define NROWS   65536
#define DIMS    64
#define KCODES  1024
#define RPB     16      // rows per block
#define NTHR    256

static constexpr size_t QST_OFF  = 0;         // quantized_st [65536*64]
static constexpr size_t LOSS_OFF = 4194304;   // loss scalar
static constexpr size_t PERP_OFF = 4194305;   // perplexity scalar
static constexpr size_t ENC_OFF  = 4194306;   // encodings [65536*1024]
static constexpr size_t IDX_OFF  = 71303170;  // encoding_indices [65536]
static constexpr size_t DIST_OFF = 71368706;  // distances [65536*1024]

// ||e_k||^2 replicating np.sum(np.square(emb), 0): sequential row-by-row,
// square rounded separately from the add (no fma).
__global__ void enorm_kernel(const float* __restrict__ emb, float* __restrict__ enorm) {
    #pragma clang fp contract(off)
    int k = blockIdx.x * blockDim.x + threadIdx.x;   // 0..1023
    float s = 0.f;
    for (int d = 0; d < DIMS; ++d) {
        float e  = emb[(size_t)d * KCODES + k];
        float sq = e * e;
        s = s + sq;
    }
    enorm[k] = s;
}

__global__ __launch_bounds__(NTHR) void vq_main(
    const float* __restrict__ x, const float* __restrict__ emb,
    const float* __restrict__ enorm, float* __restrict__ out,
    float* __restrict__ counts, float* __restrict__ sqsum)
{
    #pragma clang fp contract(off)
    __shared__ __align__(16) float xs[RPB * DIMS];
    __shared__ float xn[RPB];
    __shared__ float wbv[RPB * 2]; __shared__ int wbi[RPB * 2];
    __shared__ int   winner[RPB];

    const int tid  = threadIdx.x;
    const int lane = tid & 63;
    const int wv   = tid >> 6;     // wave 0..3
    const int gid  = tid >> 7;     // row-group 0..1 (rows gid*8 .. +7)
    const int l7   = tid & 127;    // k-lane within group: k = c*512 + l7*4 + j
    const size_t n0 = (size_t)blockIdx.x * RPB;

    // stage 16 input rows (1024 floats) into LDS, coalesced float4
    ((float4*)xs)[tid] = ((const float4*)(x + n0 * DIMS))[tid];
    __syncthreads();

    // ||x||^2 replicating numpy scalar pairwise_sum (n=64 path): 8 interleaved
    // accumulators, 3-level combine; square rounded separately (no fma).
    if (tid < RPB) {
        const float* xr = xs + tid * DIMS;
        float rr[8];
        #pragma unroll
        for (int j = 0; j < 8; ++j) { float v = xr[j]; rr[j] = v * v; }
        #pragma unroll
        for (int i = 8; i < 64; i += 8) {
            #pragma unroll
            for (int j = 0; j < 8; ++j) { float v = xr[i + j]; float sq = v * v; rr[j] = rr[j] + sq; }
        }
        xn[tid] = ((rr[0] + rr[1]) + (rr[2] + rr[3])) + ((rr[4] + rr[5]) + (rr[6] + rr[7]));
    }
    __syncthreads();

    // acc[r][c*4+j] = x_{gid*8+r} . e_{c*512 + l7*4 + j}, sequential fma over d
    float acc[8][8];
    #pragma unroll
    for (int r = 0; r < 8; ++r)
        #pragma unroll
        for (int j = 0; j < 8; ++j) acc[r][j] = 0.f;

    const float* embk = emb + l7 * 4;
    const float* xbase = xs + gid * 8 * DIMS;
    #pragma unroll 1
    for (int d0 = 0; d0 < DIMS; d0 += 4) {
        float4 xv[8];
        #pragma unroll
        for (int r = 0; r < 8; ++r) xv[r] = *(const float4*)(xbase + r * DIMS + d0);   // ds_read_b128 broadcast
        #pragma unroll
        for (int c = 0; c < 2; ++c) {
            const float* ep = embk + d0 * KCODES + c * 512;
            float4 g0 = *(const float4*)(ep);
            float4 g1 = *(const float4*)(ep + KCODES);
            float4 g2 = *(const float4*)(ep + 2 * KCODES);
            float4 g3 = *(const float4*)(ep + 3 * KCODES);
            #pragma unroll
            for (int r = 0; r < 8; ++r) {
                float4 xv4 = xv[r];
                float a0 = acc[r][c*4+0], a1 = acc[r][c*4+1], a2 = acc[r][c*4+2], a3 = acc[r][c*4+3];
                a0 = fmaf(xv4.x, g0.x, a0); a0 = fmaf(xv4.y, g1.x, a0); a0 = fmaf(xv4.z, g2.x, a0); a0 = fmaf(xv4.w, g3.x, a0);
                a1 = fmaf(xv4.x, g0.y, a1); a1 = fmaf(xv4.y, g1.y, a1); a1 = fmaf(xv4.z, g2.y, a1); a1 = fmaf(xv4.w, g3.y, a1);
                a2 = fmaf(xv4.x, g0.z, a2); a2 = fmaf(xv4.y, g1.z, a2); a2 = fmaf(xv4.z, g2.z, a2); a2 = fmaf(xv4.w, g3.z, a2);
                a3 = fmaf(xv4.x, g0.w, a3); a3 = fmaf(xv4.y, g1.w, a3); a3 = fmaf(xv4.z, g2.w, a3); a3 = fmaf(xv4.w, g3.w, a3);
                acc[r][c*4+0] = a0; acc[r][c*4+1] = a1; acc[r][c*4+2] = a2; acc[r][c*4+3] = a3;
            }
        }
    }

    const float4 e0 = *(const float4*)(enorm + l7 * 4);
    const float4 e1 = *(const float4*)(enorm + 512 + l7 * 4);
    float* distb = out + DIST_OFF;
    float* encb  = out + ENC_OFF;

    #pragma unroll
    for (int r = 0; r < 8; ++r) {
        const int row = gid * 8 + r;
        const float xnr = xn[row];
        // replicate np expression order: (xn - 2*M) + en, each op rounded
        float dv[8];
        { float m = 2.0f * acc[r][0]; float t = xnr - m; dv[0] = t + e0.x; }
        { float m = 2.0f * acc[r][1]; float t = xnr - m; dv[1] = t + e0.y; }
        { float m = 2.0f * acc[r][2]; float t = xnr - m; dv[2] = t + e0.z; }
        { float m = 2.0f * acc[r][3]; float t = xnr - m; dv[3] = t + e0.w; }
        { float m = 2.0f * acc[r][4]; float t = xnr - m; dv[4] = t + e1.x; }
        { float m = 2.0f * acc[r][5]; float t = xnr - m; dv[5] = t + e1.y; }
        { float m = 2.0f * acc[r][6]; float t = xnr - m; dv[6] = t + e1.z; }
        { float m = 2.0f * acc[r][7]; float t = xnr - m; dv[7] = t + e1.w; }

        float* dr = distb + (n0 + row) * (size_t)KCODES + l7 * 4;
        *(float2*)(dr)       = make_float2(dv[0], dv[1]);
        *(float2*)(dr + 2)   = make_float2(dv[2], dv[3]);
        *(float2*)(dr + 512) = make_float2(dv[4], dv[5]);
        *(float2*)(dr + 514) = make_float2(dv[6], dv[7]);
        float* er = encb + (n0 + row) * (size_t)KCODES + l7 * 4;
        const float2 z2 = make_float2(0.f, 0.f);
        *(float2*)(er) = z2; *(float2*)(er + 2) = z2;
        *(float2*)(er + 512) = z2; *(float2*)(er + 514) = z2;

        // local argmin, k ascending (strict less = first-index tie-break)
        float bv = dv[0]; int bi = l7 * 4;
        if (dv[1] < bv) { bv = dv[1]; bi = l7 * 4 + 1; }
        if (dv[2] < bv) { bv = dv[2]; bi = l7 * 4 + 2; }
        if (dv[3] < bv) { bv = dv[3]; bi = l7 * 4 + 3; }
        if (dv[4] < bv) { bv = dv[4]; bi = 512 + l7 * 4; }
        if (dv[5] < bv) { bv = dv[5]; bi = 512 + l7 * 4 + 1; }
        if (dv[6] < bv) { bv = dv[6]; bi = 512 + l7 * 4 + 2; }
        if (dv[7] < bv) { bv = dv[7]; bi = 512 + l7 * 4 + 3; }

        // wave-wide argmin butterfly with smaller-index tie-break
        #pragma unroll
        for (int m = 1; m < 64; m <<= 1) {
            float ov = __shfl_xor(bv, m); int oi = __shfl_xor(bi, m);
            if (ov < bv || (ov == bv && oi < bi)) { bv = ov; bi = oi; }
        }
        if (lane == 0) { wbv[row * 2 + (wv & 1)] = bv; wbi[row * 2 + (wv & 1)] = bi; }
    }

    __syncthreads();   // also orders encodings zero-stores before the 1.0 store

    if (tid < RPB) {
        float bv = wbv[tid * 2]; int bi = wbi[tid * 2];
        float ov = wbv[tid * 2 + 1]; int oi = wbi[tid * 2 + 1];
        if (ov < bv || (ov == bv && oi < bi)) { bv = ov; bi = oi; }
        winner[tid] = bi;
        out[IDX_OFF + n0 + tid] = (float)bi;
        atomicAdd(&counts[bi], 1.0f);
        encb[(n0 + tid) * (size_t)KCODES + bi] = 1.0f;
    }
    __syncthreads();

    // gather winner embedding, write quantized_st, accumulate squared error
    {
        int r  = tid >> 4;
        int dd = (tid & 15) * 4;
        int kk = winner[r];
        float4 q;
        q.x = emb[(size_t)(dd + 0) * KCODES + kk];
        q.y = emb[(size_t)(dd + 1) * KCODES + kk];
        q.z = emb[(size_t)(dd + 2) * KCODES + kk];
        q.w = emb[(size_t)(dd + 3) * KCODES + kk];
        *(float4*)(out + QST_OFF + (n0 + r) * DIMS + dd) = q;
        float f0 = q.x - xs[r*DIMS+dd+0], f1 = q.y - xs[r*DIMS+dd+1];
        float f2 = q.z - xs[r*DIMS+dd+2], f3 = q.w - xs[r*DIMS+dd+3];
        float ls = f0*f0 + f1*f1 + f2*f2 + f3*f3;
        #pragma unroll
        for (int m = 1; m < 64; m <<= 1) ls += __shfl_xor(ls, m);
        if (lane == 0) atomicAdd(sqsum, ls);
    }
}

__global__ void vq_final(const float* __restrict__ counts, const float* __restrict__ sqsum,
                         float* __restrict__ out) {
    __shared__ double part[16];
    int tid = threadIdx.x;  // 1024 threads
    double p = (double)counts[tid] * (1.0 / 65536.0);
    double t = p * log(p + 1e-10);
    #pragma unroll
    for (int m = 1; m < 64; m <<= 1) t += __shfl_xor(t, m);
    if ((tid & 63) == 0) part[tid >> 6] = t;
    __syncthreads();
    if (tid == 0) {
        double s = 0.0;
        #pragma unroll
        for (int i = 0; i < 16; ++i) s += part[i];
        out[LOSS_OFF] = (float)(1.25 * (double)sqsum[0] * (1.0 / 4194304.0));
        out[PERP_OFF] = (float)exp(-s);
    }
}

extern "C" void kernel_launch(void* const* d_in, const int* in_sizes, int n_in,
                              void* d_out, int out_size, void* d_ws, size_t ws_size,
                              hipStream_t stream) {
    const float* x   = (const float*)d_in[0];   // (64,32,32,64) fp32
    const float* emb = (const float*)d_in[1];   // (64,1024) fp32
    float* out    = (float*)d_out;
    float* enorm  = (float*)d_ws;      // [1024]
    float* counts = enorm + KCODES;    // [1024]
    float* sqsum  = counts + KCODES;   // [1]

    // ws is poisoned once and never re-poisoned: zero accumulators every call
    hipMemsetAsync(counts, 0, (KCODES + 1) * sizeof(float), stream);
    enorm_kernel<<<KCODES / NTHR, NTHR, 0, stream>>>(emb, enorm);
    vq_main<<<NROWS / RPB, NTHR, 0, stream>>>(x, emb, enorm, out, counts, sqsum);
    vq_final<<<1, KCODES, 0, stream>>>(counts, sqsum, out);
}

// Round 4
// 264.816 us; speedup vs baseline: 1.0817x; 1.0219x over previous
//
#include <hip/hip_runtime.h>
#include <math.h>

#define NROWS   65536
#define DIMS    64
#define KCODES  1024

static constexpr size_t QST_OFF  = 0;         // quantized_st [65536*64]
static constexpr size_t LOSS_OFF = 4194304;   // loss scalar
static constexpr size_t PERP_OFF = 4194305;   // perplexity scalar
static constexpr size_t ENC_OFF  = 4194306;   // encodings [65536*1024]
static constexpr size_t IDX_OFF  = 71303170;  // encoding_indices [65536]
static constexpr size_t DIST_OFF = 71368706;  // distances [65536*1024]

#define XSTRIDE 132   // pad: multiple of 4 (b128 align), odd/32 bank spread

// ||e_k||^2 replicating np.sum(np.square(emb), 0): sequential row-by-row,
// square rounded separately from the add (no fma).
__global__ void enorm_kernel(const float* __restrict__ emb, float* __restrict__ enorm) {
    #pragma clang fp contract(off)
    int k = blockIdx.x * blockDim.x + threadIdx.x;   // 0..1023
    float s = 0.f;
    for (int d = 0; d < DIMS; ++d) {
        float e  = emb[(size_t)d * KCODES + k];
        float sq = e * e;
        s = s + sq;
    }
    enorm[k] = s;
}

// Pass 1: 128-row x 128-code tile per block; dist + enc zeros + per-row
// argmin candidate via packed u64 atomicMin.
__global__ __launch_bounds__(512, 4) void vq_dist(
    const float* __restrict__ x, const float* __restrict__ emb,
    const float* __restrict__ enorm, float* __restrict__ out,
    unsigned long long* __restrict__ winners)
{
    #pragma clang fp contract(off)
    __shared__ __align__(16) float xs_t[32 * XSTRIDE];  // [d_local][row]
    __shared__ __align__(16) float es_t[32 * XSTRIDE];  // [d_local][k_local]
    __shared__ float xnl[128];

    const int tid = threadIdx.x;
    const int tc  = tid & 15;    // k-group: k_local = tc*4+{0..3} and 64+tc*4+{0..3}
    const int tr  = tid >> 4;    // row-group: rows tr*4 + {0..3}
    const int kt  = blockIdx.x & 7;          // k-tile
    const int br  = blockIdx.x >> 3;         // row-tile
    const size_t n0 = (size_t)br * 128;

    const float* xg = x + n0 * DIMS;
    const float* eg = emb + kt * 128;

    float acc[4][8];
    #pragma unroll
    for (int j = 0; j < 4; ++j)
        #pragma unroll
        for (int jj = 0; jj < 8; ++jj) acc[j][jj] = 0.f;

    float rr[8];   // ||x||^2 pairwise accumulators (threads 0..127)

    for (int h = 0; h < 2; ++h) {
        __syncthreads();   // previous half's readers done before overwrite
        // stage x half: 128 rows x 32 d, transposed
        #pragma unroll
        for (int i = 0; i < 2; ++i) {
            int c = tid + 512 * i;           // 0..1023
            int row = c >> 3, dq = c & 7;
            float4 v = *(const float4*)(xg + (size_t)row * DIMS + h * 32 + dq * 4);
            xs_t[(dq * 4 + 0) * XSTRIDE + row] = v.x;
            xs_t[(dq * 4 + 1) * XSTRIDE + row] = v.y;
            xs_t[(dq * 4 + 2) * XSTRIDE + row] = v.z;
            xs_t[(dq * 4 + 3) * XSTRIDE + row] = v.w;
        }
        // stage e half: 32 d x 128 k
        #pragma unroll
        for (int i = 0; i < 2; ++i) {
            int c = tid + 512 * i;
            int d2 = c >> 5, kq = c & 31;
            float4 v = *(const float4*)(eg + (size_t)(h * 32 + d2) * KCODES + kq * 4);
            es_t[d2 * XSTRIDE + kq * 4 + 0] = v.x;
            es_t[d2 * XSTRIDE + kq * 4 + 1] = v.y;
            es_t[d2 * XSTRIDE + kq * 4 + 2] = v.z;
            es_t[d2 * XSTRIDE + kq * 4 + 3] = v.w;
        }
        __syncthreads();

        // numpy pairwise ||x||^2 (8 interleaved accs, mul then add, no fma),
        // d order preserved across the two halves
        if (tid < 128) {
            if (h == 0) {
                #pragma unroll
                for (int j = 0; j < 8; ++j) { float v = xs_t[j * XSTRIDE + tid]; rr[j] = v * v; }
                for (int i = 8; i < 32; i += 8)
                    #pragma unroll
                    for (int j = 0; j < 8; ++j) { float v = xs_t[(i + j) * XSTRIDE + tid]; float sq = v * v; rr[j] = rr[j] + sq; }
            } else {
                for (int i = 0; i < 32; i += 8)
                    #pragma unroll
                    for (int j = 0; j < 8; ++j) { float v = xs_t[(i + j) * XSTRIDE + tid]; float sq = v * v; rr[j] = rr[j] + sq; }
                xnl[tid] = ((rr[0] + rr[1]) + (rr[2] + rr[3])) + ((rr[4] + rr[5]) + (rr[6] + rr[7]));
            }
        }

        // FMA loop: sequential-d single-fma-chain per (row,k) — BLAS order
        #pragma unroll 4
        for (int d2 = 0; d2 < 32; ++d2) {
            float4 xr = *(const float4*)&xs_t[d2 * XSTRIDE + tr * 4];
            float4 ea = *(const float4*)&es_t[d2 * XSTRIDE + tc * 4];
            float4 eb = *(const float4*)&es_t[d2 * XSTRIDE + 64 + tc * 4];
            float xv[4] = {xr.x, xr.y, xr.z, xr.w};
            #pragma unroll
            for (int j = 0; j < 4; ++j) {
                acc[j][0] = fmaf(xv[j], ea.x, acc[j][0]);
                acc[j][1] = fmaf(xv[j], ea.y, acc[j][1]);
                acc[j][2] = fmaf(xv[j], ea.z, acc[j][2]);
                acc[j][3] = fmaf(xv[j], ea.w, acc[j][3]);
                acc[j][4] = fmaf(xv[j], eb.x, acc[j][4]);
                acc[j][5] = fmaf(xv[j], eb.y, acc[j][5]);
                acc[j][6] = fmaf(xv[j], eb.z, acc[j][6]);
                acc[j][7] = fmaf(xv[j], eb.w, acc[j][7]);
            }
        }
    }
    __syncthreads();   // xnl visible to all

    const float4 en0 = *(const float4*)(enorm + kt * 128 + tc * 4);
    const float4 en1 = *(const float4*)(enorm + kt * 128 + 64 + tc * 4);
    const float4 z4 = make_float4(0.f, 0.f, 0.f, 0.f);

    #pragma unroll
    for (int j = 0; j < 4; ++j) {
        const int row = tr * 4 + j;
        const float xnr = xnl[row];
        // np expression order: (xn - 2*M) + en, each op individually rounded
        float4 da, db;
        { float m = 2.0f * acc[j][0]; float t = xnr - m; da.x = t + en0.x; }
        { float m = 2.0f * acc[j][1]; float t = xnr - m; da.y = t + en0.y; }
        { float m = 2.0f * acc[j][2]; float t = xnr - m; da.z = t + en0.z; }
        { float m = 2.0f * acc[j][3]; float t = xnr - m; da.w = t + en0.w; }
        { float m = 2.0f * acc[j][4]; float t = xnr - m; db.x = t + en1.x; }
        { float m = 2.0f * acc[j][5]; float t = xnr - m; db.y = t + en1.y; }
        { float m = 2.0f * acc[j][6]; float t = xnr - m; db.z = t + en1.z; }
        { float m = 2.0f * acc[j][7]; float t = xnr - m; db.w = t + en1.w; }

        const size_t rowg = n0 + row;
        float* dr = out + DIST_OFF + rowg * (size_t)KCODES + kt * 128 + tc * 4;
        *(float4*)dr = da; *(float4*)(dr + 64) = db;
        float* er = out + ENC_OFF + rowg * (size_t)KCODES + kt * 128 + tc * 4;
        *(float4*)er = z4; *(float4*)(er + 64) = z4;

        // local argmin, ascending k (strict less = first-index tie-break)
        float bv = da.x; int kloc = tc * 4;
        if (da.y < bv) { bv = da.y; kloc = tc * 4 + 1; }
        if (da.z < bv) { bv = da.z; kloc = tc * 4 + 2; }
        if (da.w < bv) { bv = da.w; kloc = tc * 4 + 3; }
        if (db.x < bv) { bv = db.x; kloc = 64 + tc * 4; }
        if (db.y < bv) { bv = db.y; kloc = 64 + tc * 4 + 1; }
        if (db.z < bv) { bv = db.z; kloc = 64 + tc * 4 + 2; }
        if (db.w < bv) { bv = db.w; kloc = 64 + tc * 4 + 3; }

        // monotone float->u32 map (exact float-compare order), k in low bits
        int ib = __float_as_int(bv);
        unsigned mk = (unsigned)ib ^ ((unsigned)(ib >> 31) | 0x80000000u);
        unsigned long long key = ((unsigned long long)mk << 32) | (unsigned)(kt * 128 + kloc);

        // row-mates are 16 contiguous lanes: u64 min butterfly
        #pragma unroll
        for (int m = 1; m < 16; m <<= 1) {
            unsigned long long ok = __shfl_xor(key, m);
            if (ok < key) key = ok;
        }
        if (tc == 0) atomicMin(&winners[rowg], key);
    }
}

// Pass 2: unpack winners -> qst gather, idx, enc one-hot, counts, sqsum
__global__ __launch_bounds__(256) void vq_finish(
    const float* __restrict__ x, const float* __restrict__ emb,
    const unsigned long long* __restrict__ winners, float* __restrict__ out,
    float* __restrict__ counts, float* __restrict__ sqsum)
{
    __shared__ float bsum[4];
    const int tid = threadIdx.x;
    const size_t row = (size_t)blockIdx.x * 16 + (tid >> 4);
    const int q = tid & 15;
    const int k = (int)(winners[row] & 1023u);

    float4 e4;
    e4.x = emb[(size_t)(q * 4 + 0) * KCODES + k];
    e4.y = emb[(size_t)(q * 4 + 1) * KCODES + k];
    e4.z = emb[(size_t)(q * 4 + 2) * KCODES + k];
    e4.w = emb[(size_t)(q * 4 + 3) * KCODES + k];
    float4 x4 = *(const float4*)(x + row * DIMS + q * 4);
    *(float4*)(out + QST_OFF + row * DIMS + q * 4) = e4;

    float f0 = e4.x - x4.x, f1 = e4.y - x4.y, f2 = e4.z - x4.z, f3 = e4.w - x4.w;
    float ls = f0 * f0 + f1 * f1 + f2 * f2 + f3 * f3;
    #pragma unroll
    for (int m = 1; m < 64; m <<= 1) ls += __shfl_xor(ls, m);
    if ((tid & 63) == 0) bsum[tid >> 6] = ls;

    if (q == 0) {
        out[IDX_OFF + row] = (float)k;
        atomicAdd(&counts[k], 1.0f);
        out[ENC_OFF + row * (size_t)KCODES + k] = 1.0f;   // zeros written by vq_dist (prior kernel)
    }
    __syncthreads();
    if (tid == 0) atomicAdd(sqsum, (bsum[0] + bsum[1]) + (bsum[2] + bsum[3]));
}

__global__ void vq_final(const float* __restrict__ counts, const float* __restrict__ sqsum,
                         float* __restrict__ out) {
    __shared__ double part[16];
    int tid = threadIdx.x;  // 1024 threads
    double p = (double)counts[tid] * (1.0 / 65536.0);
    double t = p * log(p + 1e-10);
    #pragma unroll
    for (int m = 1; m < 64; m <<= 1) t += __shfl_xor(t, m);
    if ((tid & 63) == 0) part[tid >> 6] = t;
    __syncthreads();
    if (tid == 0) {
        double s = 0.0;
        #pragma unroll
        for (int i = 0; i < 16; ++i) s += part[i];
        out[LOSS_OFF] = (float)(1.25 * (double)sqsum[0] * (1.0 / 4194304.0));
        out[PERP_OFF] = (float)exp(-s);
    }
}

extern "C" void kernel_launch(void* const* d_in, const int* in_sizes, int n_in,
                              void* d_out, int out_size, void* d_ws, size_t ws_size,
                              hipStream_t stream) {
    const float* x   = (const float*)d_in[0];   // (64,32,32,64) fp32
    const float* emb = (const float*)d_in[1];   // (64,1024) fp32
    float* out = (float*)d_out;
    // ws layout (floats): enorm[0,1024) | counts[1024,2048) | sqsum[2048] |
    // pad to 4096 | winners u64 [65536] at float-offset 4096  (~528 KB total)
    float* enorm  = (float*)d_ws;
    float* counts = enorm + KCODES;
    float* sqsum  = counts + KCODES;
    unsigned long long* winners = (unsigned long long*)((float*)d_ws + 4096);

    hipMemsetAsync(counts, 0, (KCODES + 1) * sizeof(float), stream);
    hipMemsetAsync(winners, 0xFF, NROWS * sizeof(unsigned long long), stream);
    enorm_kernel<<<KCODES / 256, 256, 0, stream>>>(emb, enorm);
    vq_dist<<<(NROWS / 128) * (KCODES / 128), 512, 0, stream>>>(x, emb, enorm, out, winners);
    vq_finish<<<NROWS / 16, 256, 0, stream>>>(x, emb, winners, out, counts, sqsum);
    vq_final<<<1, KCODES, 0, stream>>>(counts, sqsum, out);
}